// Round 2
// baseline (732.424 us; speedup 1.0000x reference)
//
#include <hip/hip_runtime.h>
#include <stdint.h>

// Shapes (fixed by the reference)
//   B=4, T=2048, D=1024, H=16, HD=64, K=4 templates, VOCAB=32000
// Pipeline:
//   cvt(x,Wqkv,Wout) -> bf16
//   {Q,K,V} = x @ Wqkv^T        (bf16 MFMA GEMM, m97 structure, split outputs)
//   attn = causal_flash_attn    (bf16 MFMA + online softmax)
//   y = attn + 0.1 * sum_k emb[seq_k]   (in-place)
//   out = y @ Wout^T + bout     (fp32 out)
// Memory: Q + xbf + weights in d_ws (40 MB); K,V live in d_out (32 MB scratch,
// overwritten by the final GEMM).

typedef __attribute__((ext_vector_type(8))) short s16x8;
typedef __attribute__((ext_vector_type(4))) short s16x4;
typedef __attribute__((ext_vector_type(4))) float f32x4;

static __device__ __forceinline__ unsigned short f32_bf16(float f) {
  union { float f; unsigned u; } v; v.f = f;
  unsigned r = v.u + 0x7fffu + ((v.u >> 16) & 1u);
  return (unsigned short)(r >> 16);
}
static __device__ __forceinline__ float bf16_f32(unsigned short h) {
  union { float f; unsigned u; } v; v.u = ((unsigned)h) << 16;
  return v.f;
}

// ---------------------------------------------------------------- convert
__global__ __launch_bounds__(256) void cvt_f32_bf16_k(
    const float* __restrict__ in, unsigned short* __restrict__ out, int n8) {
  int i = blockIdx.x * 256 + threadIdx.x;
  if (i >= n8) return;
  const float4* p = (const float4*)(in + (long)i * 8);
  float4 a = p[0], b = p[1];
  s16x8 o;
  o[0] = (short)f32_bf16(a.x); o[1] = (short)f32_bf16(a.y);
  o[2] = (short)f32_bf16(a.z); o[3] = (short)f32_bf16(a.w);
  o[4] = (short)f32_bf16(b.x); o[5] = (short)f32_bf16(b.y);
  o[6] = (short)f32_bf16(b.z); o[7] = (short)f32_bf16(b.w);
  *(s16x8*)(out + (long)i * 8) = o;
}

// ---------------------------------------------------------------- GEMM
// C[M,N] = A[M,K] * B[N,K]^T, bf16 inputs, 128x128 tile, BK=32, 4 waves.
__device__ __forceinline__ void glds16(const void* g, void* l) {
  __builtin_amdgcn_global_load_lds(
      (const __attribute__((address_space(1))) void*)g,
      (__attribute__((address_space(3))) void*)l, 16, 0, 0);
}

// OUTMODE 1: f32 out + bias into C0 (row stride N)
// OUTMODE 2: bf16 split-qkv out — bn<8 -> C0(Q), bn<16 -> C1(K), else C2(V),
//            each with row stride 1024
template <int OUTMODE>
__global__ __launch_bounds__(256) void gemm_bt(
    const unsigned short* __restrict__ A,   // [M][K] bf16
    const unsigned short* __restrict__ Bm,  // [N][K] bf16
    void* __restrict__ C0, void* __restrict__ C1, void* __restrict__ C2,
    const float* __restrict__ bias, int M, int N, int K) {
  __shared__ unsigned short Asl[128 * 32];
  __shared__ unsigned short Bsl[128 * 32];
  const int tid = threadIdx.x;
  const int l = tid & 63;
  const int w = tid >> 6;
  const int wr = w >> 1, wc = w & 1;
  const int bm = blockIdx.y, bn = blockIdx.x;

  f32x4 acc[4][4] = {};

  const unsigned short* Ag = A + (long)(bm * 128 + w * 16 + (l >> 2)) * K + (l & 3) * 8;
  const unsigned short* Bg = Bm + (long)(bn * 128 + w * 16 + (l >> 2)) * K + (l & 3) * 8;
  unsigned short* Al0 = &Asl[w * 512];
  unsigned short* Bl0 = &Bsl[w * 512];
  const int ro = (l & 15) * 32 + (l >> 4) * 8;  // frag: row l&15, k-offset 8*(l>>4)

  for (int k0 = 0; k0 < K; k0 += 32) {
    __syncthreads();
    glds16(Ag + k0, Al0);
    glds16(Ag + 64 * K + k0, Al0 + 2048);
    glds16(Bg + k0, Bl0);
    glds16(Bg + 64 * K + k0, Bl0 + 2048);
    __syncthreads();  // compiler emits vmcnt(0) before barrier
    s16x8 af[4], bfr[4];
#pragma unroll
    for (int i = 0; i < 4; ++i)
      af[i] = *(const s16x8*)&Asl[(wr * 64 + i * 16) * 32 + ro];
#pragma unroll
    for (int j = 0; j < 4; ++j)
      bfr[j] = *(const s16x8*)&Bsl[(wc * 64 + j * 16) * 32 + ro];
#pragma unroll
    for (int i = 0; i < 4; ++i)
#pragma unroll
      for (int j = 0; j < 4; ++j)
        acc[i][j] = __builtin_amdgcn_mfma_f32_16x16x32_bf16(af[i], bfr[j], acc[i][j], 0, 0, 0);
  }

  // C/D layout (m89-verified): col = l&15, row = 4*(l>>4) + r
  const int crow = bm * 128 + wr * 64 + (l >> 4) * 4;
  if (OUTMODE == 2) {
    unsigned short* C = (unsigned short*)(bn < 8 ? C0 : (bn < 16 ? C1 : C2));
    const int colb = (bn & 7) * 128 + wc * 64 + (l & 15);
#pragma unroll
    for (int i = 0; i < 4; ++i)
#pragma unroll
      for (int j = 0; j < 4; ++j)
#pragma unroll
        for (int r = 0; r < 4; ++r)
          C[(long)(crow + i * 16 + r) * 1024 + colb + j * 16] = f32_bf16(acc[i][j][r]);
  } else {
    float* C = (float*)C0;
    const int ccol = bn * 128 + wc * 64 + (l & 15);
#pragma unroll
    for (int i = 0; i < 4; ++i)
#pragma unroll
      for (int j = 0; j < 4; ++j) {
        float bv = bias[ccol + j * 16];
#pragma unroll
        for (int r = 0; r < 4; ++r)
          C[(long)(crow + i * 16 + r) * N + ccol + j * 16] = acc[i][j][r] + bv;
      }
  }
}

// ---------------------------------------------------------------- attention
// Q,K,V: [8192][1024] bf16, head h at cols h*64..h*64+64.
// Block: 64 q-rows (4 waves x 16), KV tiles of 32, causal. attn out bf16.
__global__ __launch_bounds__(256) void attn_k(
    const unsigned short* __restrict__ Qb, const unsigned short* __restrict__ Kb,
    const unsigned short* __restrict__ Vb, unsigned short* __restrict__ attn) {
  __shared__ unsigned short Ksl[32 * 72];  // [kv][hd], stride 72 (bank spread)
  __shared__ unsigned short Vtl[64 * 40];  // [hd][kv], stride 40
  __shared__ unsigned short Psl[64 * 40];  // [q][kv]
  const int tid = threadIdx.x;
  const int l = tid & 63;
  const int w = tid >> 6;
  const int qb = blockIdx.x;  // 0..31
  const int bh = blockIdx.y;  // 0..63
  const int b = bh >> 4, h = bh & 15;
  const int tok0 = b * 2048;
  const unsigned short* Qp = Qb + (long)tok0 * 1024 + h * 64;
  const unsigned short* Kp = Kb + (long)tok0 * 1024 + h * 64;
  const unsigned short* Vp = Vb + (long)tok0 * 1024 + h * 64;

  s16x8 qf[2];
  {
    const unsigned short* qr =
        Qp + (long)(qb * 64 + w * 16 + (l & 15)) * 1024 + (l >> 4) * 8;
    qf[0] = *(const s16x8*)qr;
    qf[1] = *(const s16x8*)(qr + 32);
  }
  f32x4 o[4] = {};
  float mrun[4] = {-1e30f, -1e30f, -1e30f, -1e30f};
  float lrun[4] = {0.f, 0.f, 0.f, 0.f};

  const int kvr = tid >> 3;      // 0..31 staged kv row
  const int kc = (tid & 7) * 8;  // hd chunk
  const int ntiles = 2 * qb + 2;
  const int qrow0 = qb * 64 + w * 16 + (l >> 4) * 4;

  for (int it = 0; it < ntiles; ++it) {
    const int kv0 = it * 32;
    __syncthreads();  // prior iter's LDS reads done
    {
      s16x8 kd = *(const s16x8*)(Kp + (long)(kv0 + kvr) * 1024 + kc);
      *(s16x8*)&Ksl[kvr * 72 + kc] = kd;
      s16x8 vd = *(const s16x8*)(Vp + (long)(kv0 + kvr) * 1024 + kc);
#pragma unroll
      for (int e = 0; e < 8; ++e) Vtl[(kc + e) * 40 + kvr] = (unsigned short)vd[e];
    }
    __syncthreads();

    // S[16q x 32kv] = Q K^T
    f32x4 s[2] = {};
#pragma unroll
    for (int st = 0; st < 2; ++st) {
      s16x8 kf0 = *(const s16x8*)&Ksl[(l & 15) * 72 + st * 32 + (l >> 4) * 8];
      s16x8 kf1 = *(const s16x8*)&Ksl[(16 + (l & 15)) * 72 + st * 32 + (l >> 4) * 8];
      s[0] = __builtin_amdgcn_mfma_f32_16x16x32_bf16(qf[st], kf0, s[0], 0, 0, 0);
      s[1] = __builtin_amdgcn_mfma_f32_16x16x32_bf16(qf[st], kf1, s[1], 0, 0, 0);
    }

    // online softmax (rows in 16-lane groups; 4 rows per lane group)
    float p0a[4], p1a[4], corr[4];
#pragma unroll
    for (int r = 0; r < 4; ++r) {
      const int q_ = qrow0 + r;
      float s0 = s[0][r] * 0.125f;
      float s1 = s[1][r] * 0.125f;
      if (kv0 + (l & 15) > q_) s0 = -1e30f;
      if (kv0 + 16 + (l & 15) > q_) s1 = -1e30f;
      float mx = fmaxf(s0, s1);
      mx = fmaxf(mx, __shfl_xor(mx, 1));
      mx = fmaxf(mx, __shfl_xor(mx, 2));
      mx = fmaxf(mx, __shfl_xor(mx, 4));
      mx = fmaxf(mx, __shfl_xor(mx, 8));
      const float mn = fmaxf(mrun[r], mx);
      const float c = __expf(mrun[r] - mn);
      mrun[r] = mn;
      const float p0 = __expf(s0 - mn);
      const float p1 = __expf(s1 - mn);
      float rs = p0 + p1;
      rs += __shfl_xor(rs, 1);
      rs += __shfl_xor(rs, 2);
      rs += __shfl_xor(rs, 4);
      rs += __shfl_xor(rs, 8);
      lrun[r] = lrun[r] * c + rs;
      corr[r] = c;
      p0a[r] = p0;
      p1a[r] = p1;
    }
#pragma unroll
    for (int ct = 0; ct < 4; ++ct)
#pragma unroll
      for (int r = 0; r < 4; ++r) o[ct][r] *= corr[r];

    // P -> LDS (bf16), then PV via MFMA
#pragma unroll
    for (int r = 0; r < 4; ++r) {
      Psl[(w * 16 + (l >> 4) * 4 + r) * 40 + (l & 15)] = f32_bf16(p0a[r]);
      Psl[(w * 16 + (l >> 4) * 4 + r) * 40 + 16 + (l & 15)] = f32_bf16(p1a[r]);
    }
    __syncthreads();
    {
      s16x8 pf = *(const s16x8*)&Psl[(w * 16 + (l & 15)) * 40 + (l >> 4) * 8];
#pragma unroll
      for (int ct = 0; ct < 4; ++ct) {
        s16x8 vf = *(const s16x8*)&Vtl[(ct * 16 + (l & 15)) * 40 + (l >> 4) * 8];
        o[ct] = __builtin_amdgcn_mfma_f32_16x16x32_bf16(pf, vf, o[ct], 0, 0, 0);
      }
    }
  }

  unsigned short* ap = attn + (long)(tok0 + qrow0) * 1024 + h * 64 + (l & 15);
#pragma unroll
  for (int r = 0; r < 4; ++r) {
    const float inv = 1.0f / lrun[r];
#pragma unroll
    for (int ct = 0; ct < 4; ++ct)
      ap[(long)r * 1024 + ct * 16] = f32_bf16(o[ct][r] * inv);
  }
}

// ---------------------------------------------------------------- gather + add
__global__ __launch_bounds__(256) void gather_add_k(
    unsigned short* __restrict__ attn, const int* __restrict__ seq,
    const float* __restrict__ emb, const float* __restrict__ bsc) {
  const int t = blockIdx.x;
  const int d0 = threadIdx.x * 4;
  const float sc = bsc[0];
  const int s0 = seq[t * 4 + 0], s1 = seq[t * 4 + 1];
  const int s2 = seq[t * 4 + 2], s3 = seq[t * 4 + 3];
  float4 e0 = *(const float4*)(emb + (long)s0 * 1024 + d0);
  float4 e1 = *(const float4*)(emb + (long)s1 * 1024 + d0);
  float4 e2 = *(const float4*)(emb + (long)s2 * 1024 + d0);
  float4 e3 = *(const float4*)(emb + (long)s3 * 1024 + d0);
  unsigned short* ap = attn + (long)t * 1024 + d0;
  s16x4 av = *(const s16x4*)ap;
  float r0 = bf16_f32((unsigned short)av[0]) + sc * (e0.x + e1.x + e2.x + e3.x);
  float r1 = bf16_f32((unsigned short)av[1]) + sc * (e0.y + e1.y + e2.y + e3.y);
  float r2 = bf16_f32((unsigned short)av[2]) + sc * (e0.z + e1.z + e2.z + e3.z);
  float r3 = bf16_f32((unsigned short)av[3]) + sc * (e0.w + e1.w + e2.w + e3.w);
  s16x4 ov;
  ov[0] = (short)f32_bf16(r0); ov[1] = (short)f32_bf16(r1);
  ov[2] = (short)f32_bf16(r2); ov[3] = (short)f32_bf16(r3);
  *(s16x4*)ap = ov;
}

// ---------------------------------------------------------------- launch
extern "C" void kernel_launch(void* const* d_in, const int* in_sizes, int n_in,
                              void* d_out, int out_size, void* d_ws, size_t ws_size,
                              hipStream_t stream) {
  const float* x = (const float*)d_in[0];
  const int* seq = (const int*)d_in[1];
  const float* Wqkv = (const float*)d_in[2];
  const float* Wout = (const float*)d_in[3];
  const float* bout = (const float*)d_in[4];
  const float* emb = (const float*)d_in[5];
  const float* bsc = (const float*)d_in[6];

  uint8_t* ws = (uint8_t*)d_ws;
  // ws layout: xbf 16MB (reused as attn/y) | wqkv 6MB | wout 2MB | Q 16MB  = 40MB
  unsigned short* xbf = (unsigned short*)ws;
  unsigned short* wqkvb = (unsigned short*)(ws + 16777216);
  unsigned short* woutb = (unsigned short*)(ws + 23068672);
  unsigned short* Qb = (unsigned short*)(ws + 25165824);
  // K,V scratch inside d_out (32MB fp32 output buffer; overwritten at the end)
  unsigned short* Kb = (unsigned short*)d_out;
  unsigned short* Vb = Kb + (long)8192 * 1024;

  cvt_f32_bf16_k<<<4096, 256, 0, stream>>>(x, xbf, 1048576);      // 8192*1024
  cvt_f32_bf16_k<<<1536, 256, 0, stream>>>(Wqkv, wqkvb, 393216);  // 3072*1024
  cvt_f32_bf16_k<<<512, 256, 0, stream>>>(Wout, woutb, 131072);   // 1024*1024

  gemm_bt<2><<<dim3(24, 64), 256, 0, stream>>>(xbf, wqkvb, Qb, Kb, Vb, nullptr,
                                               8192, 3072, 1024);
  attn_k<<<dim3(32, 64), 256, 0, stream>>>(Qb, Kb, Vb, xbf);
  gather_add_k<<<8192, 256, 0, stream>>>(xbf, seq, emb, bsc);
  gemm_bt<1><<<dim3(8, 64), 256, 0, stream>>>(xbf, woutb, d_out, nullptr, nullptr,
                                              bout, 8192, 1024, 1024);
}

// Round 3
// 475.793 us; speedup vs baseline: 1.5394x; 1.5394x over previous
//
#include <hip/hip_runtime.h>
#include <stdint.h>

// Shapes: B=4, T=2048, D=1024, H=16, HD=64, K=4 templates, VOCAB=32000
// Pipeline:
//   cvt(x,Wqkv,Wout) -> bf16
//   {Q,K,V} = x @ Wqkv^T        (bf16 MFMA GEMM, m97 structure, split outputs)
//   attn = causal_flash_attn    (bf16 MFMA, KVBLK=64, paired q-tiles, prefetch)
//   y = attn + 0.1 * sum_k emb[seq_k]   (in-place)
//   out = y @ Wout^T + bout     (fp32 out)
// Memory: Q + xbf + weights in d_ws (40 MB); K,V live in d_out (32 MB scratch).

typedef __attribute__((ext_vector_type(8))) short s16x8;
typedef __attribute__((ext_vector_type(4))) short s16x4;
typedef __attribute__((ext_vector_type(4))) float f32x4;

static __device__ __forceinline__ unsigned short f32_bf16(float f) {
  union { float f; unsigned u; } v; v.f = f;
  unsigned r = v.u + 0x7fffu + ((v.u >> 16) & 1u);
  return (unsigned short)(r >> 16);
}
static __device__ __forceinline__ float bf16_f32(unsigned short h) {
  union { float f; unsigned u; } v; v.u = ((unsigned)h) << 16;
  return v.f;
}

// ---------------------------------------------------------------- convert
__global__ __launch_bounds__(256) void cvt_f32_bf16_k(
    const float* __restrict__ in, unsigned short* __restrict__ out, int n8) {
  int i = blockIdx.x * 256 + threadIdx.x;
  if (i >= n8) return;
  const float4* p = (const float4*)(in + (long)i * 8);
  float4 a = p[0], b = p[1];
  s16x8 o;
  o[0] = (short)f32_bf16(a.x); o[1] = (short)f32_bf16(a.y);
  o[2] = (short)f32_bf16(a.z); o[3] = (short)f32_bf16(a.w);
  o[4] = (short)f32_bf16(b.x); o[5] = (short)f32_bf16(b.y);
  o[6] = (short)f32_bf16(b.z); o[7] = (short)f32_bf16(b.w);
  *(s16x8*)(out + (long)i * 8) = o;
}

// ---------------------------------------------------------------- GEMM
__device__ __forceinline__ void glds16(const void* g, void* l) {
  __builtin_amdgcn_global_load_lds(
      (const __attribute__((address_space(1))) void*)g,
      (__attribute__((address_space(3))) void*)l, 16, 0, 0);
}

// OUTMODE 1: f32 out + bias into C0 (row stride N)
// OUTMODE 2: bf16 split-qkv out, row stride 1024 (bn<8 Q, <16 K, else V)
template <int OUTMODE>
__global__ __launch_bounds__(256) void gemm_bt(
    const unsigned short* __restrict__ A,   // [M][K] bf16
    const unsigned short* __restrict__ Bm,  // [N][K] bf16
    void* __restrict__ C0, void* __restrict__ C1, void* __restrict__ C2,
    const float* __restrict__ bias, int M, int N, int K) {
  __shared__ unsigned short Asl[128 * 32];
  __shared__ unsigned short Bsl[128 * 32];
  const int tid = threadIdx.x;
  const int l = tid & 63;
  const int w = tid >> 6;
  const int wr = w >> 1, wc = w & 1;
  const int bm = blockIdx.y, bn = blockIdx.x;

  f32x4 acc[4][4] = {};

  const unsigned short* Ag = A + (long)(bm * 128 + w * 16 + (l >> 2)) * K + (l & 3) * 8;
  const unsigned short* Bg = Bm + (long)(bn * 128 + w * 16 + (l >> 2)) * K + (l & 3) * 8;
  unsigned short* Al0 = &Asl[w * 512];
  unsigned short* Bl0 = &Bsl[w * 512];
  const int ro = (l & 15) * 32 + (l >> 4) * 8;

  for (int k0 = 0; k0 < K; k0 += 32) {
    __syncthreads();
    glds16(Ag + k0, Al0);
    glds16(Ag + 64 * K + k0, Al0 + 2048);
    glds16(Bg + k0, Bl0);
    glds16(Bg + 64 * K + k0, Bl0 + 2048);
    __syncthreads();
    s16x8 af[4], bfr[4];
#pragma unroll
    for (int i = 0; i < 4; ++i)
      af[i] = *(const s16x8*)&Asl[(wr * 64 + i * 16) * 32 + ro];
#pragma unroll
    for (int j = 0; j < 4; ++j)
      bfr[j] = *(const s16x8*)&Bsl[(wc * 64 + j * 16) * 32 + ro];
#pragma unroll
    for (int i = 0; i < 4; ++i)
#pragma unroll
      for (int j = 0; j < 4; ++j)
        acc[i][j] = __builtin_amdgcn_mfma_f32_16x16x32_bf16(af[i], bfr[j], acc[i][j], 0, 0, 0);
  }

  const int crow = bm * 128 + wr * 64 + (l >> 4) * 4;
  if (OUTMODE == 2) {
    unsigned short* C = (unsigned short*)(bn < 8 ? C0 : (bn < 16 ? C1 : C2));
    const int colb = (bn & 7) * 128 + wc * 64 + (l & 15);
#pragma unroll
    for (int i = 0; i < 4; ++i)
#pragma unroll
      for (int j = 0; j < 4; ++j)
#pragma unroll
        for (int r = 0; r < 4; ++r)
          C[(long)(crow + i * 16 + r) * 1024 + colb + j * 16] = f32_bf16(acc[i][j][r]);
  } else {
    float* C = (float*)C0;
    const int ccol = bn * 128 + wc * 64 + (l & 15);
#pragma unroll
    for (int i = 0; i < 4; ++i)
#pragma unroll
      for (int j = 0; j < 4; ++j) {
        float bv = bias[ccol + j * 16];
#pragma unroll
        for (int r = 0; r < 4; ++r)
          C[(long)(crow + i * 16 + r) * N + ccol + j * 16] = acc[i][j][r] + bv;
      }
  }
}

// ---------------------------------------------------------------- attention
// Q,K,V: [8192][1024] bf16, head h at cols h*64..h*64+64.
// Block bx handles q-tiles {bx, 31-bx} (64 rows each) of head bh -> uniform
// work (33 tile-computes/block). KVBLK=64, prefetch K/V into regs (T14).
// LDS strides all 72 u16 (16B-aligned rows, conflict-free b128 reads).
// V stored transposed [d][kv] with kv ^= 8*(d>>4) swizzle (breaks bank collapse).

__device__ __forceinline__ void attn_tile(
    const unsigned short* __restrict__ Ksl, const unsigned short* __restrict__ Vtl,
    unsigned short* Psl, const s16x8* qf, f32x4* o, float* m, float* lsum,
    int qt0, int kv0, bool diag, int w, int g, int d15) {
  f32x4 s[4] = {};
#pragma unroll
  for (int st = 0; st < 4; ++st)
#pragma unroll
    for (int kc = 0; kc < 2; ++kc) {
      s16x8 kf = *(const s16x8*)&Ksl[(st * 16 + d15) * 72 + kc * 32 + g * 8];
      s[st] = __builtin_amdgcn_mfma_f32_16x16x32_bf16(qf[kc], kf, s[st], 0, 0, 0);
    }
#pragma unroll
  for (int r = 0; r < 4; ++r) {
    const int qabs = qt0 + w * 16 + g * 4 + r;
    float sv0 = s[0][r] * 0.125f, sv1 = s[1][r] * 0.125f;
    float sv2 = s[2][r] * 0.125f, sv3 = s[3][r] * 0.125f;
    if (diag) {
      if (kv0 + d15 > qabs) sv0 = -1e30f;
      if (kv0 + 16 + d15 > qabs) sv1 = -1e30f;
      if (kv0 + 32 + d15 > qabs) sv2 = -1e30f;
      if (kv0 + 48 + d15 > qabs) sv3 = -1e30f;
    }
    float mx = fmaxf(fmaxf(sv0, sv1), fmaxf(sv2, sv3));
    mx = fmaxf(mx, __shfl_xor(mx, 1));
    mx = fmaxf(mx, __shfl_xor(mx, 2));
    mx = fmaxf(mx, __shfl_xor(mx, 4));
    mx = fmaxf(mx, __shfl_xor(mx, 8));
    const float mn = fmaxf(m[r], mx);
    const float c = __expf(m[r] - mn);
    m[r] = mn;
    const float p0 = __expf(sv0 - mn), p1 = __expf(sv1 - mn);
    const float p2 = __expf(sv2 - mn), p3 = __expf(sv3 - mn);
    unsigned short* pr = &Psl[(w * 16 + g * 4 + r) * 72 + d15];
    pr[0] = f32_bf16(p0); pr[16] = f32_bf16(p1);
    pr[32] = f32_bf16(p2); pr[48] = f32_bf16(p3);
    float rsum = (p0 + p1) + (p2 + p3);
    rsum += __shfl_xor(rsum, 1);
    rsum += __shfl_xor(rsum, 2);
    rsum += __shfl_xor(rsum, 4);
    rsum += __shfl_xor(rsum, 8);
    lsum[r] = lsum[r] * c + rsum;
#pragma unroll
    for (int ct = 0; ct < 4; ++ct) o[ct][r] *= c;
  }
  // P re-read + PV are wave-local (rows w*16..w*16+15): DS ops are in-order
  // within a wave -> no barrier needed.
#pragma unroll
  for (int kc2 = 0; kc2 < 2; ++kc2) {
    s16x8 pf = *(const s16x8*)&Psl[(w * 16 + d15) * 72 + kc2 * 32 + g * 8];
#pragma unroll
    for (int ct = 0; ct < 4; ++ct) {
      s16x8 vf = *(const s16x8*)&Vtl[(ct * 16 + d15) * 72 + ((kc2 * 32 + g * 8) ^ (ct * 8))];
      o[ct] = __builtin_amdgcn_mfma_f32_16x16x32_bf16(pf, vf, o[ct], 0, 0, 0);
    }
  }
}

__global__ __launch_bounds__(256) void attn_k(
    const unsigned short* __restrict__ Qb, const unsigned short* __restrict__ Kb,
    const unsigned short* __restrict__ Vb, unsigned short* __restrict__ attn) {
  __shared__ unsigned short Ksl[64 * 72];  // [kv][hd]
  __shared__ unsigned short Vtl[64 * 72];  // [hd][kv^swz]
  __shared__ unsigned short Psl[64 * 72];  // [q][kv]
  const int tid = threadIdx.x;
  const int l = tid & 63;
  const int w = tid >> 6;
  const int g = l >> 4;
  const int d15 = l & 15;
  const int bx = blockIdx.x;  // 0..15
  const int bh = blockIdx.y;  // 0..63
  const int b = bh >> 4, h = bh & 15;
  const int tok0 = b * 2048;
  const int qA = bx, qB = 31 - bx;
  const int nA = qA + 1, ntiles = qB + 1;
  const unsigned short* Qp = Qb + (long)tok0 * 1024 + h * 64;
  const unsigned short* Kp = Kb + (long)tok0 * 1024 + h * 64;
  const unsigned short* Vp = Vb + (long)tok0 * 1024 + h * 64;

  s16x8 qfA[2], qfB[2];
  {
    const unsigned short* qa = Qp + (long)(qA * 64 + w * 16 + d15) * 1024 + g * 8;
    qfA[0] = *(const s16x8*)qa;
    qfA[1] = *(const s16x8*)(qa + 32);
    const unsigned short* qbp = Qp + (long)(qB * 64 + w * 16 + d15) * 1024 + g * 8;
    qfB[0] = *(const s16x8*)qbp;
    qfB[1] = *(const s16x8*)(qbp + 32);
  }
  f32x4 oA[4] = {}, oB[4] = {};
  float mA[4], lA[4], mB[4], lB[4];
#pragma unroll
  for (int r = 0; r < 4; ++r) {
    mA[r] = -1e30f; lA[r] = 0.f; mB[r] = -1e30f; lB[r] = 0.f;
  }

  // staging: thread -> kv row rs_ (0..63), d cols c0..c0+15 (two 16B chunks)
  const int rs_ = tid >> 2;
  const int c0 = (tid & 3) * 16;
  const int vswz = rs_ ^ ((c0 >> 4) * 8);  // kv ^ 8*(d>>4), d>>4 == c0>>4
  const unsigned short* Kg = Kp + (long)rs_ * 1024 + c0;
  const unsigned short* Vg = Vp + (long)rs_ * 1024 + c0;
  s16x8 kp0 = *(const s16x8*)Kg, kp1 = *(const s16x8*)(Kg + 8);
  s16x8 vp0 = *(const s16x8*)Vg, vp1 = *(const s16x8*)(Vg + 8);

  for (int it = 0; it < ntiles; ++it) {
    __syncthreads();  // prev-iter LDS reads complete
    *(s16x8*)&Ksl[rs_ * 72 + c0] = kp0;
    *(s16x8*)&Ksl[rs_ * 72 + c0 + 8] = kp1;
#pragma unroll
    for (int e = 0; e < 8; ++e) {
      Vtl[(c0 + e) * 72 + vswz] = (unsigned short)vp0[e];
      Vtl[(c0 + 8 + e) * 72 + vswz] = (unsigned short)vp1[e];
    }
    if (it + 1 < ntiles) {  // prefetch next tile; latency hides under compute
      Kg += 65536; Vg += 65536;
      kp0 = *(const s16x8*)Kg; kp1 = *(const s16x8*)(Kg + 8);
      vp0 = *(const s16x8*)Vg; vp1 = *(const s16x8*)(Vg + 8);
    }
    __syncthreads();  // staging visible
    attn_tile(Ksl, Vtl, Psl, qfB, oB, mB, lB, qB * 64, it * 64, it == qB, w, g, d15);
    if (it < nA)
      attn_tile(Ksl, Vtl, Psl, qfA, oA, mA, lA, qA * 64, it * 64, it == qA, w, g, d15);
  }

  unsigned short* apB = attn + (long)(tok0 + qB * 64 + w * 16 + g * 4) * 1024 + h * 64 + d15;
  unsigned short* apA = attn + (long)(tok0 + qA * 64 + w * 16 + g * 4) * 1024 + h * 64 + d15;
#pragma unroll
  for (int r = 0; r < 4; ++r) {
    const float invB = 1.0f / lB[r];
    const float invA = 1.0f / lA[r];
#pragma unroll
    for (int ct = 0; ct < 4; ++ct) {
      apB[(long)r * 1024 + ct * 16] = f32_bf16(oB[ct][r] * invB);
      apA[(long)r * 1024 + ct * 16] = f32_bf16(oA[ct][r] * invA);
    }
  }
}

// ---------------------------------------------------------------- gather + add
__global__ __launch_bounds__(256) void gather_add_k(
    unsigned short* __restrict__ attn, const int* __restrict__ seq,
    const float* __restrict__ emb, const float* __restrict__ bsc) {
  const int t = blockIdx.x;
  const int d0 = threadIdx.x * 4;
  const float sc = bsc[0];
  const int s0 = seq[t * 4 + 0], s1 = seq[t * 4 + 1];
  const int s2 = seq[t * 4 + 2], s3 = seq[t * 4 + 3];
  float4 e0 = *(const float4*)(emb + (long)s0 * 1024 + d0);
  float4 e1 = *(const float4*)(emb + (long)s1 * 1024 + d0);
  float4 e2 = *(const float4*)(emb + (long)s2 * 1024 + d0);
  float4 e3 = *(const float4*)(emb + (long)s3 * 1024 + d0);
  unsigned short* ap = attn + (long)t * 1024 + d0;
  s16x4 av = *(const s16x4*)ap;
  float r0 = bf16_f32((unsigned short)av[0]) + sc * (e0.x + e1.x + e2.x + e3.x);
  float r1 = bf16_f32((unsigned short)av[1]) + sc * (e0.y + e1.y + e2.y + e3.y);
  float r2 = bf16_f32((unsigned short)av[2]) + sc * (e0.z + e1.z + e2.z + e3.z);
  float r3 = bf16_f32((unsigned short)av[3]) + sc * (e0.w + e1.w + e2.w + e3.w);
  s16x4 ov;
  ov[0] = (short)f32_bf16(r0); ov[1] = (short)f32_bf16(r1);
  ov[2] = (short)f32_bf16(r2); ov[3] = (short)f32_bf16(r3);
  *(s16x4*)ap = ov;
}

// ---------------------------------------------------------------- launch
extern "C" void kernel_launch(void* const* d_in, const int* in_sizes, int n_in,
                              void* d_out, int out_size, void* d_ws, size_t ws_size,
                              hipStream_t stream) {
  const float* x = (const float*)d_in[0];
  const int* seq = (const int*)d_in[1];
  const float* Wqkv = (const float*)d_in[2];
  const float* Wout = (const float*)d_in[3];
  const float* bout = (const float*)d_in[4];
  const float* emb = (const float*)d_in[5];
  const float* bsc = (const float*)d_in[6];

  uint8_t* ws = (uint8_t*)d_ws;
  unsigned short* xbf = (unsigned short*)ws;                  // 16MB, reused as attn/y
  unsigned short* wqkvb = (unsigned short*)(ws + 16777216);   // 6MB
  unsigned short* woutb = (unsigned short*)(ws + 23068672);   // 2MB
  unsigned short* Qb = (unsigned short*)(ws + 25165824);      // 16MB
  unsigned short* Kb = (unsigned short*)d_out;                // scratch in d_out
  unsigned short* Vb = Kb + (long)8192 * 1024;

  cvt_f32_bf16_k<<<4096, 256, 0, stream>>>(x, xbf, 1048576);
  cvt_f32_bf16_k<<<1536, 256, 0, stream>>>(Wqkv, wqkvb, 393216);
  cvt_f32_bf16_k<<<512, 256, 0, stream>>>(Wout, woutb, 131072);

  gemm_bt<2><<<dim3(24, 64), 256, 0, stream>>>(xbf, wqkvb, Qb, Kb, Vb, nullptr,
                                               8192, 3072, 1024);
  attn_k<<<dim3(16, 64), 256, 0, stream>>>(Qb, Kb, Vb, xbf);
  gather_add_k<<<8192, 256, 0, stream>>>(xbf, seq, emb, bsc);
  gemm_bt<1><<<dim3(8, 64), 256, 0, stream>>>(xbf, woutb, d_out, nullptr, nullptr,
                                              bout, 8192, 1024, 1024);
}

// Round 4
// 435.266 us; speedup vs baseline: 1.6827x; 1.0931x over previous
//
#include <hip/hip_runtime.h>
#include <stdint.h>

// Shapes: B=4, T=2048, D=1024, H=16, HD=64, K=4 templates, VOCAB=32000
// Pipeline:
//   cvt(x,Wqkv,Wout) -> bf16
//   {Q,K,V} = x @ Wqkv^T   (bf16 MFMA GEMM; Q pre-scaled by 0.125*log2e)
//   attn = causal_flash_attn (bf16 MFMA, log2-domain softmax, deferred l-reduce)
//          + fused emb-gather add in epilogue
//   out = y @ Wout^T + bout  (fp32 out)
// Memory: Q + xbf + weights in d_ws (40 MB); K,V live in d_out (32 MB scratch).

typedef __attribute__((ext_vector_type(8))) short s16x8;
typedef __attribute__((ext_vector_type(4))) short s16x4;
typedef __attribute__((ext_vector_type(4))) float f32x4;

static __device__ __forceinline__ unsigned short f32_bf16(float f) {
  union { float f; unsigned u; } v; v.f = f;
  unsigned r = v.u + 0x7fffu + ((v.u >> 16) & 1u);
  return (unsigned short)(r >> 16);
}
static __device__ __forceinline__ float bf16_f32(unsigned short h) {
  union { float f; unsigned u; } v; v.u = ((unsigned)h) << 16;
  return v.f;
}
static __device__ __forceinline__ float fexp2(float x) {
#if __has_builtin(__builtin_amdgcn_exp2f)
  return __builtin_amdgcn_exp2f(x);
#else
  return exp2f(x);
#endif
}

// ---------------------------------------------------------------- convert
__global__ __launch_bounds__(256) void cvt_f32_bf16_k(
    const float* __restrict__ in, unsigned short* __restrict__ out, int n8) {
  int i = blockIdx.x * 256 + threadIdx.x;
  if (i >= n8) return;
  const float4* p = (const float4*)(in + (long)i * 8);
  float4 a = p[0], b = p[1];
  s16x8 o;
  o[0] = (short)f32_bf16(a.x); o[1] = (short)f32_bf16(a.y);
  o[2] = (short)f32_bf16(a.z); o[3] = (short)f32_bf16(a.w);
  o[4] = (short)f32_bf16(b.x); o[5] = (short)f32_bf16(b.y);
  o[6] = (short)f32_bf16(b.z); o[7] = (short)f32_bf16(b.w);
  *(s16x8*)(out + (long)i * 8) = o;
}

// ---------------------------------------------------------------- GEMM
__device__ __forceinline__ void glds16(const void* g, void* l) {
  __builtin_amdgcn_global_load_lds(
      (const __attribute__((address_space(1))) void*)g,
      (__attribute__((address_space(3))) void*)l, 16, 0, 0);
}

// OUTMODE 1: f32 out + bias into C0 (row stride N)
// OUTMODE 2: bf16 split-qkv out, row stride 1024 (bn<8 Q [pre-scaled], <16 K, else V)
template <int OUTMODE>
__global__ __launch_bounds__(256) void gemm_bt(
    const unsigned short* __restrict__ A,   // [M][K] bf16
    const unsigned short* __restrict__ Bm,  // [N][K] bf16
    void* __restrict__ C0, void* __restrict__ C1, void* __restrict__ C2,
    const float* __restrict__ bias, int M, int N, int K) {
  __shared__ unsigned short Asl[128 * 32];
  __shared__ unsigned short Bsl[128 * 32];
  const int tid = threadIdx.x;
  const int l = tid & 63;
  const int w = tid >> 6;
  const int wr = w >> 1, wc = w & 1;
  const int bm = blockIdx.y, bn = blockIdx.x;

  f32x4 acc[4][4] = {};

  const unsigned short* Ag = A + (long)(bm * 128 + w * 16 + (l >> 2)) * K + (l & 3) * 8;
  const unsigned short* Bg = Bm + (long)(bn * 128 + w * 16 + (l >> 2)) * K + (l & 3) * 8;
  unsigned short* Al0 = &Asl[w * 512];
  unsigned short* Bl0 = &Bsl[w * 512];
  const int ro = (l & 15) * 32 + (l >> 4) * 8;

  for (int k0 = 0; k0 < K; k0 += 32) {
    __syncthreads();
    glds16(Ag + k0, Al0);
    glds16(Ag + 64 * K + k0, Al0 + 2048);
    glds16(Bg + k0, Bl0);
    glds16(Bg + 64 * K + k0, Bl0 + 2048);
    __syncthreads();
    s16x8 af[4], bfr[4];
#pragma unroll
    for (int i = 0; i < 4; ++i)
      af[i] = *(const s16x8*)&Asl[(wr * 64 + i * 16) * 32 + ro];
#pragma unroll
    for (int j = 0; j < 4; ++j)
      bfr[j] = *(const s16x8*)&Bsl[(wc * 64 + j * 16) * 32 + ro];
#pragma unroll
    for (int i = 0; i < 4; ++i)
#pragma unroll
      for (int j = 0; j < 4; ++j)
        acc[i][j] = __builtin_amdgcn_mfma_f32_16x16x32_bf16(af[i], bfr[j], acc[i][j], 0, 0, 0);
  }

  const int crow = bm * 128 + wr * 64 + (l >> 4) * 4;
  if (OUTMODE == 2) {
    unsigned short* C = (unsigned short*)(bn < 8 ? C0 : (bn < 16 ? C1 : C2));
    // Q gets pre-scaled by 1/sqrt(64) * log2(e) so attn softmax runs in exp2 domain
    const float qsc = (bn < 8) ? 0.18033688f : 1.0f;
    const int colb = (bn & 7) * 128 + wc * 64 + (l & 15);
#pragma unroll
    for (int i = 0; i < 4; ++i)
#pragma unroll
      for (int j = 0; j < 4; ++j)
#pragma unroll
        for (int r = 0; r < 4; ++r)
          C[(long)(crow + i * 16 + r) * 1024 + colb + j * 16] = f32_bf16(acc[i][j][r] * qsc);
  } else {
    float* C = (float*)C0;
    const int ccol = bn * 128 + wc * 64 + (l & 15);
#pragma unroll
    for (int i = 0; i < 4; ++i)
#pragma unroll
      for (int j = 0; j < 4; ++j) {
        float bv = bias[ccol + j * 16];
#pragma unroll
        for (int r = 0; r < 4; ++r)
          C[(long)(crow + i * 16 + r) * N + ccol + j * 16] = acc[i][j][r] + bv;
      }
  }
}

// ---------------------------------------------------------------- attention
// Q,K,V: [8192][1024] bf16, head h at cols h*64..h*64+64. Q is pre-scaled.
// Block bx handles q-tiles {bx, 31-bx} (64 rows each) of head bh; KVBLK=64.
// Softmax in log2 domain (exp2), per-lane deferred l-sum, setprio on MFMA.
// Epilogue fuses the template-embedding gather-add for this head's 64 cols.

__device__ __forceinline__ void attn_tile(
    const unsigned short* __restrict__ Ksl, const unsigned short* __restrict__ Vtl,
    unsigned short* Psl, const s16x8* qf, f32x4* o, float* m, float* lpart,
    int qt0, int kv0, bool diag, int w, int g, int d15) {
  f32x4 s[4] = {};
  __builtin_amdgcn_s_setprio(1);
#pragma unroll
  for (int st = 0; st < 4; ++st)
#pragma unroll
    for (int kc = 0; kc < 2; ++kc) {
      s16x8 kf = *(const s16x8*)&Ksl[(st * 16 + d15) * 72 + kc * 32 + g * 8];
      s[st] = __builtin_amdgcn_mfma_f32_16x16x32_bf16(qf[kc], kf, s[st], 0, 0, 0);
    }
  __builtin_amdgcn_s_setprio(0);
#pragma unroll
  for (int r = 0; r < 4; ++r) {
    const int qabs = qt0 + w * 16 + g * 4 + r;
    float sv0 = s[0][r], sv1 = s[1][r], sv2 = s[2][r], sv3 = s[3][r];
    if (diag) {
      if (kv0 + d15 > qabs) sv0 = -1e30f;
      if (kv0 + 16 + d15 > qabs) sv1 = -1e30f;
      if (kv0 + 32 + d15 > qabs) sv2 = -1e30f;
      if (kv0 + 48 + d15 > qabs) sv3 = -1e30f;
    }
    float mx = fmaxf(fmaxf(sv0, sv1), fmaxf(sv2, sv3));
    mx = fmaxf(mx, __shfl_xor(mx, 1));
    mx = fmaxf(mx, __shfl_xor(mx, 2));
    mx = fmaxf(mx, __shfl_xor(mx, 4));
    mx = fmaxf(mx, __shfl_xor(mx, 8));
    const float mn = fmaxf(m[r], mx);
    const float c = fexp2(m[r] - mn);  // log2-domain rescale
    m[r] = mn;
    const float p0 = fexp2(sv0 - mn), p1 = fexp2(sv1 - mn);
    const float p2 = fexp2(sv2 - mn), p3 = fexp2(sv3 - mn);
    unsigned short* pr = &Psl[(w * 16 + g * 4 + r) * 72 + d15];
    pr[0] = f32_bf16(p0); pr[16] = f32_bf16(p1);
    pr[32] = f32_bf16(p2); pr[48] = f32_bf16(p3);
    // deferred l: per-lane partial only (c is row-uniform across the 16 lanes)
    lpart[r] = lpart[r] * c + ((p0 + p1) + (p2 + p3));
#pragma unroll
    for (int ct = 0; ct < 4; ++ct) o[ct][r] *= c;
  }
  // P re-read + PV are wave-local: DS ops in-order within a wave, no barrier.
  __builtin_amdgcn_s_setprio(1);
#pragma unroll
  for (int kc2 = 0; kc2 < 2; ++kc2) {
    s16x8 pf = *(const s16x8*)&Psl[(w * 16 + d15) * 72 + kc2 * 32 + g * 8];
#pragma unroll
    for (int ct = 0; ct < 4; ++ct) {
      s16x8 vf = *(const s16x8*)&Vtl[(ct * 16 + d15) * 72 + ((kc2 * 32 + g * 8) ^ (ct * 8))];
      o[ct] = __builtin_amdgcn_mfma_f32_16x16x32_bf16(pf, vf, o[ct], 0, 0, 0);
    }
  }
  __builtin_amdgcn_s_setprio(0);
}

__global__ __launch_bounds__(256) void attn_k(
    const unsigned short* __restrict__ Qb, const unsigned short* __restrict__ Kb,
    const unsigned short* __restrict__ Vb, unsigned short* __restrict__ attn,
    const int* __restrict__ seq, const float* __restrict__ emb,
    const float* __restrict__ bsc) {
  __shared__ unsigned short Ksl[64 * 72];  // [kv][hd]
  __shared__ unsigned short Vtl[64 * 72];  // [hd][kv^swz]
  __shared__ unsigned short Psl[64 * 72];  // [q][kv]
  const int tid = threadIdx.x;
  const int l = tid & 63;
  const int w = tid >> 6;
  const int g = l >> 4;
  const int d15 = l & 15;
  const int bx = blockIdx.x;  // 0..15
  const int bh = blockIdx.y;  // 0..63
  const int b = bh >> 4, h = bh & 15;
  const int tok0 = b * 2048;
  const int qA = bx, qB = 31 - bx;
  const int nA = qA + 1, ntiles = qB + 1;
  const unsigned short* Qp = Qb + (long)tok0 * 1024 + h * 64;
  const unsigned short* Kp = Kb + (long)tok0 * 1024 + h * 64;
  const unsigned short* Vp = Vb + (long)tok0 * 1024 + h * 64;

  s16x8 qfA[2], qfB[2];
  {
    const unsigned short* qa = Qp + (long)(qA * 64 + w * 16 + d15) * 1024 + g * 8;
    qfA[0] = *(const s16x8*)qa;
    qfA[1] = *(const s16x8*)(qa + 32);
    const unsigned short* qbp = Qp + (long)(qB * 64 + w * 16 + d15) * 1024 + g * 8;
    qfB[0] = *(const s16x8*)qbp;
    qfB[1] = *(const s16x8*)(qbp + 32);
  }
  f32x4 oA[4] = {}, oB[4] = {};
  float mA[4], lA[4], mB[4], lB[4];
#pragma unroll
  for (int r = 0; r < 4; ++r) {
    mA[r] = -1e30f; lA[r] = 0.f; mB[r] = -1e30f; lB[r] = 0.f;
  }

  const int rs_ = tid >> 2;
  const int c0 = (tid & 3) * 16;
  const int vswz = rs_ ^ ((c0 >> 4) * 8);
  const unsigned short* Kg = Kp + (long)rs_ * 1024 + c0;
  const unsigned short* Vg = Vp + (long)rs_ * 1024 + c0;
  s16x8 kp0 = *(const s16x8*)Kg, kp1 = *(const s16x8*)(Kg + 8);
  s16x8 vp0 = *(const s16x8*)Vg, vp1 = *(const s16x8*)(Vg + 8);

  for (int it = 0; it < ntiles; ++it) {
    __syncthreads();
    *(s16x8*)&Ksl[rs_ * 72 + c0] = kp0;
    *(s16x8*)&Ksl[rs_ * 72 + c0 + 8] = kp1;
#pragma unroll
    for (int e = 0; e < 8; ++e) {
      Vtl[(c0 + e) * 72 + vswz] = (unsigned short)vp0[e];
      Vtl[(c0 + 8 + e) * 72 + vswz] = (unsigned short)vp1[e];
    }
    if (it + 1 < ntiles) {
      Kg += 65536; Vg += 65536;
      kp0 = *(const s16x8*)Kg; kp1 = *(const s16x8*)(Kg + 8);
      vp0 = *(const s16x8*)Vg; vp1 = *(const s16x8*)(Vg + 8);
    }
    __syncthreads();
    attn_tile(Ksl, Vtl, Psl, qfB, oB, mB, lB, qB * 64, it * 64, it == qB, w, g, d15);
    if (it < nA)
      attn_tile(Ksl, Vtl, Psl, qfA, oA, mA, lA, qA * 64, it * 64, it == qA, w, g, d15);
  }

  // final l reduction (deferred from the loop)
#pragma unroll
  for (int r = 0; r < 4; ++r) {
    float sB = lB[r], sA = lA[r];
    sB += __shfl_xor(sB, 1); sB += __shfl_xor(sB, 2);
    sB += __shfl_xor(sB, 4); sB += __shfl_xor(sB, 8);
    sA += __shfl_xor(sA, 1); sA += __shfl_xor(sA, 2);
    sA += __shfl_xor(sA, 4); sA += __shfl_xor(sA, 8);
    lB[r] = sB; lA[r] = sA;
  }

  // epilogue: normalize + fused template-embedding add for this head's cols
  const float sc = bsc[0];
  const int colbase = h * 64 + d15;
  const int tB0 = tok0 + qB * 64 + w * 16 + g * 4;
  const int tA0 = tok0 + qA * 64 + w * 16 + g * 4;
  unsigned short* apB = attn + (long)tB0 * 1024 + colbase;
  unsigned short* apA = attn + (long)tA0 * 1024 + colbase;
#pragma unroll
  for (int r = 0; r < 4; ++r) {
    const float invB = 1.0f / lB[r];
    const float invA = 1.0f / lA[r];
    const int* sqB = seq + (long)(tB0 + r) * 4;
    const int* sqA = seq + (long)(tA0 + r) * 4;
    const float* eB0 = emb + (long)sqB[0] * 1024 + colbase;
    const float* eB1 = emb + (long)sqB[1] * 1024 + colbase;
    const float* eB2 = emb + (long)sqB[2] * 1024 + colbase;
    const float* eB3 = emb + (long)sqB[3] * 1024 + colbase;
    const float* eA0 = emb + (long)sqA[0] * 1024 + colbase;
    const float* eA1 = emb + (long)sqA[1] * 1024 + colbase;
    const float* eA2 = emb + (long)sqA[2] * 1024 + colbase;
    const float* eA3 = emb + (long)sqA[3] * 1024 + colbase;
#pragma unroll
    for (int ct = 0; ct < 4; ++ct) {
      const int cc = ct * 16;
      float embB = (eB0[cc] + eB1[cc]) + (eB2[cc] + eB3[cc]);
      float embA = (eA0[cc] + eA1[cc]) + (eA2[cc] + eA3[cc]);
      apB[(long)r * 1024 + cc] = f32_bf16(oB[ct][r] * invB + sc * embB);
      apA[(long)r * 1024 + cc] = f32_bf16(oA[ct][r] * invA + sc * embA);
    }
  }
}

// ---------------------------------------------------------------- launch
extern "C" void kernel_launch(void* const* d_in, const int* in_sizes, int n_in,
                              void* d_out, int out_size, void* d_ws, size_t ws_size,
                              hipStream_t stream) {
  const float* x = (const float*)d_in[0];
  const int* seq = (const int*)d_in[1];
  const float* Wqkv = (const float*)d_in[2];
  const float* Wout = (const float*)d_in[3];
  const float* bout = (const float*)d_in[4];
  const float* emb = (const float*)d_in[5];
  const float* bsc = (const float*)d_in[6];

  uint8_t* ws = (uint8_t*)d_ws;
  unsigned short* xbf = (unsigned short*)ws;                  // 16MB, reused as y
  unsigned short* wqkvb = (unsigned short*)(ws + 16777216);   // 6MB
  unsigned short* woutb = (unsigned short*)(ws + 23068672);   // 2MB
  unsigned short* Qb = (unsigned short*)(ws + 25165824);      // 16MB
  unsigned short* Kb = (unsigned short*)d_out;                // scratch in d_out
  unsigned short* Vb = Kb + (long)8192 * 1024;

  cvt_f32_bf16_k<<<4096, 256, 0, stream>>>(x, xbf, 1048576);
  cvt_f32_bf16_k<<<1536, 256, 0, stream>>>(Wqkv, wqkvb, 393216);
  cvt_f32_bf16_k<<<512, 256, 0, stream>>>(Wout, woutb, 131072);

  gemm_bt<2><<<dim3(24, 64), 256, 0, stream>>>(xbf, wqkvb, Qb, Kb, Vb, nullptr,
                                               8192, 3072, 1024);
  attn_k<<<dim3(16, 64), 256, 0, stream>>>(Qb, Kb, Vb, xbf, seq, emb, bsc);
  gemm_bt<1><<<dim3(8, 64), 256, 0, stream>>>(xbf, woutb, d_out, nullptr, nullptr,
                                              bout, 8192, 1024, 1024);
}